// Round 1
// baseline (247.774 us; speedup 1.0000x reference)
//
#include <hip/hip_runtime.h>

#define F 128

typedef __attribute__((ext_vector_type(8))) __bf16 bf16x8;
typedef __attribute__((ext_vector_type(4))) float f32x4;
typedef __attribute__((ext_vector_type(8))) unsigned short us8;
typedef __attribute__((ext_vector_type(4))) unsigned short us4;
typedef __attribute__((ext_vector_type(2))) unsigned short us2;

__device__ __forceinline__ unsigned short f2bf(float x) {
    unsigned u = __builtin_bit_cast(unsigned, x);
    u = u + 0x7FFFu + ((u >> 16) & 1u);   // round-to-nearest-even
    return (unsigned short)(u >> 16);
}

__device__ __forceinline__ bf16x8 pack8(float4 a, float4 b) {
    us8 t;
    t[0] = f2bf(a.x); t[1] = f2bf(a.y); t[2] = f2bf(a.z); t[3] = f2bf(a.w);
    t[4] = f2bf(b.x); t[5] = f2bf(b.y); t[6] = f2bf(b.z); t[7] = f2bf(b.w);
    return __builtin_bit_cast(bf16x8, t);
}

// LDS layout (ushort units):
//  A1: [0, 26112)  : v tile bf16, 192 rows (m = c*64+nl) x stride 136 (128 used)
//  A2: [0, 16896)  : mlp_in bf16, 64 rows x stride 264 (256 used: s | ||Vv||^2)
//  A3: [16896, 25600): h bf16, 64 rows x stride 136 (128 used)
#define A1_STRIDE 136
#define A2_STRIDE 264
#define A3_BASE   16896
#define A3_STRIDE 136

__global__ __launch_bounds__(512)
void painn_fused(const float* __restrict__ s, const float* __restrict__ v,
                 const float* __restrict__ Uw, const float* __restrict__ Vw,
                 const float* __restrict__ aw1, const float* __restrict__ ab1,
                 const float* __restrict__ aw2, const float* __restrict__ ab2,
                 float* __restrict__ out, int Ntot)
{
    __shared__ unsigned short SH[26112];

    const int tid  = threadIdx.x;
    const int lane = tid & 63;
    const int w    = tid >> 6;        // wave 0..7
    const int l15  = lane & 15;
    const int kp   = lane >> 4;       // 0..3
    const int col  = (w << 4) | l15;  // g-column this lane owns, 0..127
    const int n0   = blockIdx.x * 64;
    const size_t NF = (size_t)Ntot * F;

    // ---- B fragments for U_w, V_w (global -> regs, bf16). B[k][col] = W[col][k].
    bf16x8 bU[4], bV[4];
    #pragma unroll
    for (int ks = 0; ks < 4; ++ks) {
        int k0 = (ks << 5) + (kp << 3);
        const float4* pu = (const float4*)&Uw[col * F + k0];
        bU[ks] = pack8(pu[0], pu[1]);
        const float4* pv = (const float4*)&Vw[col * F + k0];
        bV[ks] = pack8(pv[0], pv[1]);
    }

    // ---- Phase 0: stage A1 = v tile as bf16, A1[c*64+nl][f] = v[n0+nl][f][c]
    #pragma unroll
    for (int it = 0; it < 8; ++it) {
        int idx = tid + it * 512;          // 4096 tasks: 64 rows x 64 f-pairs
        int nl  = idx >> 6;
        int f0  = (idx & 63) << 1;
        int n   = n0 + nl; if (n >= Ntot) n = Ntot - 1;
        const float* src = v + ((size_t)n * F + f0) * 3;
        float2 ab = *(const float2*)(src);       // v[f0][0], v[f0][1]
        float2 cd = *(const float2*)(src + 2);   // v[f0][2], v[f0+1][0]
        float2 ef = *(const float2*)(src + 4);   // v[f0+1][1], v[f0+1][2]
        us2 p;
        p[0] = f2bf(ab.x); p[1] = f2bf(cd.y);
        *(us2*)&SH[(0 * 64 + nl) * A1_STRIDE + f0] = p;
        p[0] = f2bf(ab.y); p[1] = f2bf(ef.x);
        *(us2*)&SH[(1 * 64 + nl) * A1_STRIDE + f0] = p;
        p[0] = f2bf(cd.x); p[1] = f2bf(ef.y);
        *(us2*)&SH[(2 * 64 + nl) * A1_STRIDE + f0] = p;
    }
    __syncthreads();

    // ---- Stage 1: Uv, Vv.  C[m][col], m = c*64 + nl; 12 m-tiles per wave.
    f32x4 accU[12], accV[12];
    #pragma unroll
    for (int i = 0; i < 12; ++i) { accU[i] = (f32x4){0.f,0.f,0.f,0.f}; accV[i] = (f32x4){0.f,0.f,0.f,0.f}; }

    #pragma unroll
    for (int ks = 0; ks < 4; ++ks) {
        #pragma unroll
        for (int mt = 0; mt < 12; ++mt) {
            bf16x8 a = *(const bf16x8*)&SH[(mt * 16 + l15) * A1_STRIDE + (ks << 5) + (kp << 3)];
            accU[mt] = __builtin_amdgcn_mfma_f32_16x16x32_bf16(a, bU[ks], accU[mt], 0, 0, 0);
            accV[mt] = __builtin_amdgcn_mfma_f32_16x16x32_bf16(a, bV[ks], accV[mt], 0, 0, 0);
        }
    }

    // ---- ||Vv||^2 and <Uv,Vv>: c-reduction is per-lane (m-tiles c*4+nt share lane map)
    f32x4 nrm[4], inr[4];
    #pragma unroll
    for (int nt = 0; nt < 4; ++nt) {
        #pragma unroll
        for (int r = 0; r < 4; ++r) {
            float vn = 0.f, in = 0.f;
            #pragma unroll
            for (int c = 0; c < 3; ++c) {
                float uu = accU[c * 4 + nt][r];
                float vv = accV[c * 4 + nt][r];
                vn += vv * vv;
                in += uu * vv;
            }
            nrm[nt][r] = vn;
            inr[nt][r] = in;
        }
    }
    __syncthreads();   // everyone done reading A1

    // ---- Phase 2 staging: A2[nl][0..127] = s (bf16), A2[nl][128..255] = ||Vv||^2
    #pragma unroll
    for (int it = 0; it < 4; ++it) {
        int idx = tid + it * 512;          // 2048 tasks: 64 rows x 32 f-quads
        int nl  = idx >> 5;
        int f0  = (idx & 31) << 2;
        int n   = n0 + nl; if (n >= Ntot) n = Ntot - 1;
        float4 sv = *(const float4*)&s[(size_t)n * F + f0];
        us4 t;
        t[0] = f2bf(sv.x); t[1] = f2bf(sv.y); t[2] = f2bf(sv.z); t[3] = f2bf(sv.w);
        *(us4*)&SH[nl * A2_STRIDE + f0] = t;
    }
    #pragma unroll
    for (int nt = 0; nt < 4; ++nt) {
        #pragma unroll
        for (int r = 0; r < 4; ++r) {
            int row = nt * 16 + (kp << 2) + r;
            SH[row * A2_STRIDE + 128 + col] = f2bf(nrm[nt][r]);
        }
    }
    __syncthreads();

    // ---- Stage 2: h = shifted_softplus(mlp_in @ a_w1.T + b1)
    bf16x8 bW1[8];
    #pragma unroll
    for (int ks = 0; ks < 8; ++ks) {
        int k0 = (ks << 5) + (kp << 3);
        const float4* p = (const float4*)&aw1[col * 256 + k0];
        bW1[ks] = pack8(p[0], p[1]);
    }
    f32x4 accH[4];
    #pragma unroll
    for (int i = 0; i < 4; ++i) accH[i] = (f32x4){0.f,0.f,0.f,0.f};
    #pragma unroll
    for (int ks = 0; ks < 8; ++ks) {
        #pragma unroll
        for (int nt = 0; nt < 4; ++nt) {
            bf16x8 a = *(const bf16x8*)&SH[(nt * 16 + l15) * A2_STRIDE + (ks << 5) + (kp << 3)];
            accH[nt] = __builtin_amdgcn_mfma_f32_16x16x32_bf16(a, bW1[ks], accH[nt], 0, 0, 0);
        }
    }
    float b1 = ab1[col];
    #pragma unroll
    for (int nt = 0; nt < 4; ++nt) {
        #pragma unroll
        for (int r = 0; r < 4; ++r) {
            float x = accH[nt][r] + b1;
            // softplus(x) - log(2), numerically stable
            float hsp = fmaxf(x, 0.f) + log1pf(__expf(-fabsf(x))) - 0.69314718056f;
            int row = nt * 16 + (kp << 2) + r;
            SH[A3_BASE + row * A3_STRIDE + col] = f2bf(hsp);   // A3 doesn't overlap A2
        }
    }
    __syncthreads();

    // ---- Stage 3, block j=2 (a_vv) first: consume Uv, write v_new
    {
        bf16x8 bW2[4];
        #pragma unroll
        for (int ks = 0; ks < 4; ++ks) {
            int k0 = (ks << 5) + (kp << 3);
            const float4* p = (const float4*)&aw2[(size_t)(2 * F + col) * F + k0];
            bW2[ks] = pack8(p[0], p[1]);
        }
        f32x4 acc[4];
        #pragma unroll
        for (int i = 0; i < 4; ++i) acc[i] = (f32x4){0.f,0.f,0.f,0.f};
        #pragma unroll
        for (int ks = 0; ks < 4; ++ks) {
            #pragma unroll
            for (int nt = 0; nt < 4; ++nt) {
                bf16x8 a = *(const bf16x8*)&SH[A3_BASE + (nt * 16 + l15) * A3_STRIDE + (ks << 5) + (kp << 3)];
                acc[nt] = __builtin_amdgcn_mfma_f32_16x16x32_bf16(a, bW2[ks], acc[nt], 0, 0, 0);
            }
        }
        float b2 = ab2[2 * F + col];
        #pragma unroll
        for (int nt = 0; nt < 4; ++nt) {
            #pragma unroll
            for (int r = 0; r < 4; ++r) {
                int nl = nt * 16 + (kp << 2) + r;
                int n  = n0 + nl;
                if (n < Ntot) {
                    float avv = acc[nt][r] + b2;
                    size_t base = ((size_t)n * F + col) * 3;
                    #pragma unroll
                    for (int c = 0; c < 3; ++c) {
                        out[NF + base + c] = v[base + c] + avv * accU[c * 4 + nt][r];
                    }
                }
            }
        }
    }

    // ---- Stage 3, blocks j=0 (a_ss) and j=1 (a_sv): write s_new
    f32x4 accS[4], accT[4];
    #pragma unroll
    for (int i = 0; i < 4; ++i) { accS[i] = (f32x4){0.f,0.f,0.f,0.f}; accT[i] = (f32x4){0.f,0.f,0.f,0.f}; }
    {
        bf16x8 bW2s[4], bW2t[4];
        #pragma unroll
        for (int ks = 0; ks < 4; ++ks) {
            int k0 = (ks << 5) + (kp << 3);
            const float4* p0 = (const float4*)&aw2[(size_t)(0 * F + col) * F + k0];
            bW2s[ks] = pack8(p0[0], p0[1]);
            const float4* p1 = (const float4*)&aw2[(size_t)(1 * F + col) * F + k0];
            bW2t[ks] = pack8(p1[0], p1[1]);
        }
        #pragma unroll
        for (int ks = 0; ks < 4; ++ks) {
            #pragma unroll
            for (int nt = 0; nt < 4; ++nt) {
                bf16x8 a = *(const bf16x8*)&SH[A3_BASE + (nt * 16 + l15) * A3_STRIDE + (ks << 5) + (kp << 3)];
                accS[nt] = __builtin_amdgcn_mfma_f32_16x16x32_bf16(a, bW2s[ks], accS[nt], 0, 0, 0);
                accT[nt] = __builtin_amdgcn_mfma_f32_16x16x32_bf16(a, bW2t[ks], accT[nt], 0, 0, 0);
            }
        }
    }
    float bss = ab2[0 * F + col];
    float bsv = ab2[1 * F + col];
    #pragma unroll
    for (int nt = 0; nt < 4; ++nt) {
        #pragma unroll
        for (int r = 0; r < 4; ++r) {
            int nl = nt * 16 + (kp << 2) + r;
            int n  = n0 + nl;
            if (n < Ntot) {
                size_t o = (size_t)n * F + col;
                float a_ss = accS[nt][r] + bss;
                float a_sv = accT[nt][r] + bsv;
                out[o] = s[o] + a_ss + a_sv * inr[nt][r];
            }
        }
    }
}

extern "C" void kernel_launch(void* const* d_in, const int* in_sizes, int n_in,
                              void* d_out, int out_size, void* d_ws, size_t ws_size,
                              hipStream_t stream) {
    (void)n_in; (void)d_ws; (void)ws_size; (void)out_size;
    const float* s   = (const float*)d_in[0];
    const float* v   = (const float*)d_in[1];
    const float* Uw  = (const float*)d_in[2];
    const float* Vw  = (const float*)d_in[3];
    const float* aw1 = (const float*)d_in[4];
    const float* ab1 = (const float*)d_in[5];
    const float* aw2 = (const float*)d_in[6];
    const float* ab2 = (const float*)d_in[7];
    float* out = (float*)d_out;
    int Ntot = in_sizes[0] / F;                 // 100000
    int grid = (Ntot + 63) / 64;                // 1563
    hipLaunchKernelGGL(painn_fused, dim3(grid), dim3(512), 0, stream,
                       s, v, Uw, Vw, aw1, ab1, aw2, ab2, out, Ntot);
}